// Round 3
// baseline (195.779 us; speedup 1.0000x reference)
//
#include <hip/hip_runtime.h>

#define DIMC 1024
#define HEADS 16
#define HD 64
#define BATCH 2
#define SEQ 1024
#define NQKV 3072

typedef _Float16 f16;
typedef _Float16 half8 __attribute__((ext_vector_type(8)));
typedef _Float16 half4v __attribute__((ext_vector_type(4)));
typedef float floatx4 __attribute__((ext_vector_type(4)));

__device__ __forceinline__ void gld16(const void* g, void* l) {
  __builtin_amdgcn_global_load_lds((const __attribute__((address_space(1))) void*)g,
                                   (__attribute__((address_space(3))) void*)l, 16, 0, 0);
}

__device__ __forceinline__ unsigned sadU8(unsigned a, unsigned b, unsigned c) {
#if __has_builtin(__builtin_amdgcn_sad_u8)
  return __builtin_amdgcn_sad_u8(a, b, c);
#else
  unsigned d;
  asm("v_sad_u8 %0, %1, %2, %3" : "=v"(d) : "v"(a), "v"(b), "v"(c));
  return d;
#endif
}

// ---------------- f32 -> f16 casts (x, qkv_w, proj_w) ----------------
__global__ __launch_bounds__(256) void cvt_kernel(
    const float* __restrict__ x, const float* __restrict__ wq, const float* __restrict__ wp,
    f16* __restrict__ x16, f16* __restrict__ wq16, f16* __restrict__ wp16)
{
  long long bid = blockIdx.x;
  const float* src; f16* dst; long long base;
  if (bid < 2048)            { src = x;  dst = x16;  base = bid; }
  else if (bid < 2048+3072)  { src = wq; dst = wq16; base = bid - 2048; }
  else                       { src = wp; dst = wp16; base = bid - (2048+3072); }
  long long i = base*256 + threadIdx.x;   // float4 index
  float4 v = ((const float4*)src)[i];
  half4v h; h[0]=(f16)v.x; h[1]=(f16)v.y; h[2]=(f16)v.z; h[3]=(f16)v.w;
  *(half4v*)(dst + i*4) = h;
}

// ---------------- TM x TN f16 MFMA GEMM, C = A * Bw^T + bias ----------------
// MODE 0: QKV -> q8/k8 (u8 quant, [b,h,s,d]) and vT (f16, [b,h,d,s])
// MODE 1: proj -> f32 out [t, f]
template<int TM, int TN, int MODE>
__global__ __launch_bounds__(256, 4) void gemm_kernel(
    const f16* __restrict__ A, const f16* __restrict__ Bw, const float* __restrict__ bias,
    unsigned char* __restrict__ q8, unsigned char* __restrict__ k8, f16* __restrict__ vT,
    float* __restrict__ outp, int K)
{
  constexpr int MT = TM / 32;   // m-subtiles per wave
  constexpr int NT = TN / 32;   // n-subtiles per wave
  __shared__ f16 As[TM*64];
  __shared__ f16 Bs[TN*64];
  const int tid = threadIdx.x;
  const int wave = tid >> 6, lane = tid & 63;
  const int lq = lane >> 4, li = lane & 15;
  const int m0 = blockIdx.y * TM, n0 = blockIdx.x * TN;
  const int wm = (wave & 1) * (TM/2), wn = (wave >> 1) * (TN/2);
  floatx4 acc[MT][NT] = {};

  const int kIters = K / 64;
  for (int kt = 0; kt < kIters; ++kt) {
    __syncthreads();
#pragma unroll
    for (int r = 0; r < TM/32; ++r) {
      int slot = r*256 + tid;
      int row = slot >> 3, c = slot & 7, sc = c ^ (row & 7);
      gld16(A + (size_t)(m0+row)*K + kt*64 + sc*8, As + slot*8);
    }
#pragma unroll
    for (int r = 0; r < TN/32; ++r) {
      int slot = r*256 + tid;
      int row = slot >> 3, c = slot & 7, sc = c ^ (row & 7);
      gld16(Bw + (size_t)(n0+row)*K + kt*64 + sc*8, Bs + slot*8);
    }
    __syncthreads();
#pragma unroll
    for (int ks = 0; ks < 2; ++ks) {
      half8 af[MT], bf[NT];
      int kc = ks*4 + lq;
#pragma unroll
      for (int t = 0; t < MT; ++t) {
        int am = wm + t*16 + li;
        af[t] = *(const half8*)&As[am*64 + (kc ^ (am & 7))*8];
      }
#pragma unroll
      for (int t = 0; t < NT; ++t) {
        int bn = wn + t*16 + li;
        bf[t] = *(const half8*)&Bs[bn*64 + (kc ^ (bn & 7))*8];
      }
#pragma unroll
      for (int mt = 0; mt < MT; ++mt)
#pragma unroll
        for (int nt = 0; nt < NT; ++nt)
          acc[mt][nt] = __builtin_amdgcn_mfma_f32_16x16x32_f16(af[mt], bf[nt], acc[mt][nt], 0, 0, 0);
    }
  }

#pragma unroll
  for (int mt = 0; mt < MT; ++mt) {
#pragma unroll
    for (int nt = 0; nt < NT; ++nt) {
      int f = n0 + wn + nt*16 + li;                 // output feature (col, from B)
      float bb = bias[f];
      if (MODE == 0) {
        int which = f >> 10, cc = f & 1023, h = cc >> 6, d = cc & 63;
        int t0 = m0 + wm + mt*16 + lq*4;            // token (row, from A), 4 consecutive
        int b = t0 >> 10, s0 = t0 & 1023;
        if (which == 2) {
          half4v hv;
#pragma unroll
          for (int r = 0; r < 4; ++r) hv[r] = (f16)(acc[mt][nt][r] + bb);
          *(half4v*)&vT[((size_t)((b*HEADS + h)*HD + d))*SEQ + s0] = hv;
        } else {
          unsigned char* dst = (which == 0) ? q8 : k8;
#pragma unroll
          for (int r = 0; r < 4; ++r) {
            float v = acc[mt][nt][r] + bb;
            int u = (int)floorf(v * 16.0f + 128.5f);
            u = u < 0 ? 0 : (u > 255 ? 255 : u);
            dst[((size_t)((b*HEADS + h)*SEQ + s0 + r))*HD + d] = (unsigned char)u;
          }
        }
      } else {
#pragma unroll
        for (int r = 0; r < 4; ++r) {
          int t = m0 + wm + mt*16 + lq*4 + r;
          outp[(size_t)t*DIMC + f] = acc[mt][nt][r] + bb;
        }
      }
    }
  }
}

// ---------------- Laplacian attention + depthwise conv, y16 out ----------------
// Round-3 structure:
//  - cooperative double-buffered k staging (128 keys/iter), ONE __syncthreads/iter
//  - per-wave 32-key slice; SAD produces scores directly in MFMA A-frag registers
//  - PV B-fragments loaded straight from global vT[bh][d][s] (16B contiguous, L2-hot)
//  - q tile in LDS (broadcast reads), cross-wave O/rowsum combine via LDS atomics once
__global__ __launch_bounds__(256, 2) void attn_kernel(
    const unsigned char* __restrict__ q8g, const unsigned char* __restrict__ k8g,
    const f16* __restrict__ vTg, const float* __restrict__ dwcw, const float* __restrict__ dwcb,
    f16* __restrict__ y16)
{
  __shared__ unsigned char q8s[64*64];        //  4 KB
  __shared__ unsigned char k8s[2][128*64];    // 16 KB double-buffered key tiles
  __shared__ float Obuf[64*64];               // 16 KB cross-wave O accumulator
  __shared__ float rowsumS[64];               // 256 B
  __shared__ f16 vconv[64*66];                // 8.25 KB v window for conv

  const int tid = threadIdx.x;
  const int bh = blockIdx.y;             // b*16+h
  const int i0 = blockIdx.x * 64;
  const int lane = tid & 63, wave = tid >> 6;
  const int lq = lane >> 4, li = lane & 15;

  // zero cross-wave accumulators (EPS folded into rowsum init)
#pragma unroll
  for (int i = 0; i < 16; ++i) Obuf[tid + i*256] = 0.0f;
  if (tid < 64) rowsumS[tid] = 1e-6f;

  // stage q tile: 64 rows x 64B (contiguous)
  gld16(q8g + ((size_t)bh*SEQ + i0)*HD + tid*16, q8s + tid*16);

  { // stage conv v window [d][i0-1 .. i0+64]
    int d = tid >> 2, part = tid & 3;
    const f16* vrow = vTg + ((size_t)(bh*HD) + d)*SEQ;
#pragma unroll
    for (int e = 0; e < 17; ++e) {
      int ss = part*17 + e;
      if (ss < 66) {
        int s = i0 - 1 + ss;
        vconv[d*66 + ss] = (s >= 0 && s < SEQ) ? vrow[s] : (f16)0.0f;
      }
    }
  }

  // cooperative staging of a 128-key tile (8 KB) into buffer `buf`
  auto stageK = [&](int buf, int jb) {
    const unsigned char* kg = k8g + ((size_t)bh*SEQ + jb*128)*HD;
#pragma unroll
    for (int r = 0; r < 2; ++r) {
      int slot = r*256 + tid;
      gld16(kg + slot*16, k8s[buf] + slot*16);
    }
  };

  stageK(0, 0);
  __syncthreads();          // q/vconv/zeros visible; buf0 resident

  float rs[4] = {0.f, 0.f, 0.f, 0.f};
  floatx4 pacc[4][4] = {};

  for (int jb = 0; jb < 8; ++jb) {
    const int cur = jb & 1;
    const int j0w = jb*128 + wave*32;       // this wave's 32-key slice

    // PV B-fragments straight from global (16B contiguous; whole iter to cover latency)
    half8 bfr[4];
#pragma unroll
    for (int nt = 0; nt < 4; ++nt)
      bfr[nt] = *(const half8*)(vTg + ((size_t)(bh*HD) + nt*16 + li)*SEQ + j0w + lq*8);

    if (jb < 7) stageK(cur ^ 1, jb + 1);    // prefetch next tile

    const unsigned char* kb = k8s[cur] + wave*2048;

    // ---- SAD distances: lane -> rows {li+16n} x keys {j0w + lq*8 .. +8} ----
    unsigned sacc[4][8] = {};
#pragma unroll
    for (int p = 0; p < 4; ++p) {
      int cc = (p + lq) & 3;                // phase rotation: conflict-free LDS reads
      uint4 kk[8];
#pragma unroll
      for (int jj = 0; jj < 8; ++jj)
        kk[jj] = *(const uint4*)&kb[(lq*8 + jj)*64 + cc*16];
      uint4 qc[4];
#pragma unroll
      for (int n = 0; n < 4; ++n)
        qc[n] = *(const uint4*)&q8s[(li + n*16)*64 + cc*16];
#pragma unroll
      for (int n = 0; n < 4; ++n)
#pragma unroll
        for (int jj = 0; jj < 8; ++jj) {
          sacc[n][jj] = sadU8(qc[n].x, kk[jj].x, sacc[n][jj]);
          sacc[n][jj] = sadU8(qc[n].y, kk[jj].y, sacc[n][jj]);
          sacc[n][jj] = sadU8(qc[n].z, kk[jj].z, sacc[n][jj]);
          sacc[n][jj] = sadU8(qc[n].w, kk[jj].w, sacc[n][jj]);
        }
    }

    // kern = exp(-sad/256) -> exp2(-sad*log2e/256); scores land in A-frag regs
    half8 af[4];
#pragma unroll
    for (int n = 0; n < 4; ++n)
#pragma unroll
      for (int jj = 0; jj < 8; ++jj) {
        float sf = exp2f(-0.0056355275f * (float)sacc[n][jj]);
        rs[n] += sf;
        af[n][jj] = (f16)sf;
      }

    // ---- PV MFMA: this wave's 32-k slice, 4 m-tiles x 4 d-tiles ----
#pragma unroll
    for (int nt = 0; nt < 4; ++nt)
#pragma unroll
      for (int mt = 0; mt < 4; ++mt)
        pacc[mt][nt] = __builtin_amdgcn_mfma_f32_16x16x32_f16(af[mt], bfr[nt], pacc[mt][nt], 0, 0, 0);

    __syncthreads();   // prefetch drained; all waves done with cur before overwrite
  }

  // ---- cross-wave reduction ----
#pragma unroll
  for (int n = 0; n < 4; ++n) {
    rs[n] += __shfl_xor(rs[n], 16, 64);
    rs[n] += __shfl_xor(rs[n], 32, 64);
  }
  if (lane < 16) {
#pragma unroll
    for (int n = 0; n < 4; ++n) atomicAdd(&rowsumS[lane + n*16], rs[n]);
  }
#pragma unroll
  for (int mt = 0; mt < 4; ++mt)
#pragma unroll
    for (int nt = 0; nt < 4; ++nt)
#pragma unroll
      for (int r = 0; r < 4; ++r)
        atomicAdd(&Obuf[(mt*16 + lq*4 + r)*64 + nt*16 + li], pacc[mt][nt][r]);
  __syncthreads();

  // ---- epilogue: normalize + depthwise conv + store y16 [b,s,h*64+d] ----
  const int b = bh >> 4, h = bh & 15;
  const int r = tid >> 2, dq = tid & 3;
  float inv = 1.0f / rowsumS[r];
  half8 hv0, hv1;
#pragma unroll
  for (int e = 0; e < 16; ++e) {
    int d = dq*16 + e;
    int c = h*64 + d;
    float val = Obuf[r*64 + d] * inv
              + dwcw[c*3+0] * (float)vconv[d*66 + r]
              + dwcw[c*3+1] * (float)vconv[d*66 + r + 1]
              + dwcw[c*3+2] * (float)vconv[d*66 + r + 2]
              + dwcb[c];
    if (e < 8) hv0[e] = (f16)val; else hv1[e-8] = (f16)val;
  }
  f16* yp = y16 + ((size_t)(b*SEQ + i0 + r))*DIMC + h*64 + dq*16;
  *(half8*)yp = hv0;
  *(half8*)(yp + 8) = hv1;
}

extern "C" void kernel_launch(void* const* d_in, const int* in_sizes, int n_in,
                              void* d_out, int out_size, void* d_ws, size_t ws_size,
                              hipStream_t stream) {
  const float* x      = (const float*)d_in[0];
  const float* qkv_w  = (const float*)d_in[1];
  const float* qkv_b  = (const float*)d_in[2];
  const float* proj_w = (const float*)d_in[3];
  const float* proj_b = (const float*)d_in[4];
  const float* dwc_w  = (const float*)d_in[5];
  const float* dwc_b  = (const float*)d_in[6];
  float* out = (float*)d_out;

  char* ws = (char*)d_ws;
  f16* x16  = (f16*)(ws);                         //  4 MB
  f16* wq16 = (f16*)(ws + (4ll<<20));             //  6 MB
  f16* wp16 = (f16*)(ws + (10ll<<20));            //  2 MB
  unsigned char* q8 = (unsigned char*)(ws + (12ll<<20));  // 2 MB
  unsigned char* k8 = (unsigned char*)(ws + (14ll<<20));  // 2 MB
  f16* vT   = (f16*)(ws + (16ll<<20));            //  4 MB
  f16* y16  = (f16*)(ws + (20ll<<20));            //  4 MB (total 24 MB)

  cvt_kernel<<<6144, 256, 0, stream>>>(x, qkv_w, proj_w, x16, wq16, wp16);
  gemm_kernel<64,128,0><<<dim3(24, 32), 256, 0, stream>>>(x16, wq16, qkv_b, q8, k8, vT, nullptr, DIMC);
  attn_kernel<<<dim3(16, 32), 256, 0, stream>>>(q8, k8, vT, dwc_w, dwc_b, y16);
  gemm_kernel<64,64,1><<<dim3(16, 32), 256, 0, stream>>>(y16, wp16, proj_b, nullptr, nullptr, nullptr, out, DIMC);
}

// Round 4
// 162.016 us; speedup vs baseline: 1.2084x; 1.2084x over previous
//
#include <hip/hip_runtime.h>

#define DIMC 1024
#define HEADS 16
#define HD 64
#define BATCH 2
#define SEQ 1024
#define NQKV 3072

typedef _Float16 f16;
typedef _Float16 half8 __attribute__((ext_vector_type(8)));
typedef _Float16 half4v __attribute__((ext_vector_type(4)));
typedef float floatx4 __attribute__((ext_vector_type(4)));

__device__ __forceinline__ void gld16(const void* g, void* l) {
  __builtin_amdgcn_global_load_lds((const __attribute__((address_space(1))) void*)g,
                                   (__attribute__((address_space(3))) void*)l, 16, 0, 0);
}

__device__ __forceinline__ unsigned sadU8(unsigned a, unsigned b, unsigned c) {
#if __has_builtin(__builtin_amdgcn_sad_u8)
  return __builtin_amdgcn_sad_u8(a, b, c);
#else
  unsigned d;
  asm("v_sad_u8 %0, %1, %2, %3" : "=v"(d) : "v"(a), "v"(b), "v"(c));
  return d;
#endif
}

// ---------------- f32 -> f16 casts (x, qkv_w, proj_w) ----------------
__global__ __launch_bounds__(256) void cvt_kernel(
    const float* __restrict__ x, const float* __restrict__ wq, const float* __restrict__ wp,
    f16* __restrict__ x16, f16* __restrict__ wq16, f16* __restrict__ wp16)
{
  long long bid = blockIdx.x;
  const float* src; f16* dst; long long base;
  if (bid < 2048)            { src = x;  dst = x16;  base = bid; }
  else if (bid < 2048+3072)  { src = wq; dst = wq16; base = bid - 2048; }
  else                       { src = wp; dst = wp16; base = bid - (2048+3072); }
  long long i = base*256 + threadIdx.x;   // float4 index
  float4 v = ((const float4*)src)[i];
  half4v h; h[0]=(f16)v.x; h[1]=(f16)v.y; h[2]=(f16)v.z; h[3]=(f16)v.w;
  *(half4v*)(dst + i*4) = h;
}

// ---------------- TM x TN f16 MFMA GEMM, C = A * Bw^T + bias ----------------
// MODE 0: QKV -> q8/k8 (u8 quant, [b,h,s,d]) and vT (f16, [b,h,d,s])
// MODE 1: proj -> f32 out [t, f]
template<int TM, int TN, int MODE>
__global__ __launch_bounds__(256, 4) void gemm_kernel(
    const f16* __restrict__ A, const f16* __restrict__ Bw, const float* __restrict__ bias,
    unsigned char* __restrict__ q8, unsigned char* __restrict__ k8, f16* __restrict__ vT,
    float* __restrict__ outp, int K)
{
  constexpr int MT = TM / 32;   // m-subtiles per wave
  constexpr int NT = TN / 32;   // n-subtiles per wave
  __shared__ f16 As[TM*64];
  __shared__ f16 Bs[TN*64];
  const int tid = threadIdx.x;
  const int wave = tid >> 6, lane = tid & 63;
  const int lq = lane >> 4, li = lane & 15;
  const int m0 = blockIdx.y * TM, n0 = blockIdx.x * TN;
  const int wm = (wave & 1) * (TM/2), wn = (wave >> 1) * (TN/2);
  floatx4 acc[MT][NT] = {};

  const int kIters = K / 64;
  for (int kt = 0; kt < kIters; ++kt) {
    __syncthreads();
#pragma unroll
    for (int r = 0; r < TM/32; ++r) {
      int slot = r*256 + tid;
      int row = slot >> 3, c = slot & 7, sc = c ^ (row & 7);
      gld16(A + (size_t)(m0+row)*K + kt*64 + sc*8, As + slot*8);
    }
#pragma unroll
    for (int r = 0; r < TN/32; ++r) {
      int slot = r*256 + tid;
      int row = slot >> 3, c = slot & 7, sc = c ^ (row & 7);
      gld16(Bw + (size_t)(n0+row)*K + kt*64 + sc*8, Bs + slot*8);
    }
    __syncthreads();
#pragma unroll
    for (int ks = 0; ks < 2; ++ks) {
      half8 af[MT], bf[NT];
      int kc = ks*4 + lq;
#pragma unroll
      for (int t = 0; t < MT; ++t) {
        int am = wm + t*16 + li;
        af[t] = *(const half8*)&As[am*64 + (kc ^ (am & 7))*8];
      }
#pragma unroll
      for (int t = 0; t < NT; ++t) {
        int bn = wn + t*16 + li;
        bf[t] = *(const half8*)&Bs[bn*64 + (kc ^ (bn & 7))*8];
      }
#pragma unroll
      for (int mt = 0; mt < MT; ++mt)
#pragma unroll
        for (int nt = 0; nt < NT; ++nt)
          acc[mt][nt] = __builtin_amdgcn_mfma_f32_16x16x32_f16(af[mt], bf[nt], acc[mt][nt], 0, 0, 0);
    }
  }

#pragma unroll
  for (int mt = 0; mt < MT; ++mt) {
#pragma unroll
    for (int nt = 0; nt < NT; ++nt) {
      int f = n0 + wn + nt*16 + li;                 // output feature (col, from B)
      float bb = bias[f];
      if (MODE == 0) {
        int which = f >> 10, cc = f & 1023, h = cc >> 6, d = cc & 63;
        int t0 = m0 + wm + mt*16 + lq*4;            // token (row, from A), 4 consecutive
        int b = t0 >> 10, s0 = t0 & 1023;
        if (which == 2) {
          half4v hv;
#pragma unroll
          for (int r = 0; r < 4; ++r) hv[r] = (f16)(acc[mt][nt][r] + bb);
          *(half4v*)&vT[((size_t)((b*HEADS + h)*HD + d))*SEQ + s0] = hv;
        } else {
          unsigned char* dst = (which == 0) ? q8 : k8;
#pragma unroll
          for (int r = 0; r < 4; ++r) {
            float v = acc[mt][nt][r] + bb;
            int u = (int)floorf(v * 16.0f + 128.5f);
            u = u < 0 ? 0 : (u > 255 ? 255 : u);
            dst[((size_t)((b*HEADS + h)*SEQ + s0 + r))*HD + d] = (unsigned char)u;
          }
        }
      } else {
#pragma unroll
        for (int r = 0; r < 4; ++r) {
          int t = m0 + wm + mt*16 + lq*4 + r;
          outp[(size_t)t*DIMC + f] = acc[mt][nt][r] + bb;
        }
      }
    }
  }
}

// ---------------- Laplacian attention + depthwise conv, y16 out ----------------
// R1 skeleton (proven 45.8us) with two deltas:
//  - 32-query blocks -> 1024 blocks = 4 blocks/CU (was 2): double latency hiding
//  - PV B-fragments straight from global vT[bh][d][s] (16B contiguous, L2-hot):
//    removes vTs staging + its bank conflicts + 16KB LDS
// q cached in registers once; SAD k-reads are 16-lane broadcasts (free).
__global__ __launch_bounds__(256, 4) void attn_kernel(
    const unsigned char* __restrict__ q8g, const unsigned char* __restrict__ k8g,
    const f16* __restrict__ vTg, const float* __restrict__ dwcw, const float* __restrict__ dwcb,
    f16* __restrict__ y16)
{
  __shared__ unsigned char q8s[32*64];   //  2 KB
  __shared__ unsigned char k8s[128*64];  //  8 KB
  __shared__ f16 sfrag[8*64*8];          //  8 KB  scores in MFMA A-frag layout
  __shared__ float rspart[32*16];        //  2 KB
  __shared__ float rowsumS[32];
  __shared__ f16 vconv[64*34];           //  4.25 KB v window for conv

  const int tid = threadIdx.x;
  const int bh = blockIdx.y;             // b*16+h
  const int i0 = blockIdx.x * 32;
  const int lane = tid & 63, wave = tid >> 6;
  const int lq = lane >> 4, li = lane & 15;
  const int iL = tid & 15, jt = tid >> 4;       // phase-1 mapping
  const int ksj = jt >> 2, qj = jt & 3;
  const int mtb = wave & 1, ntb = wave >> 1;    // phase-2 wave partition

  // stage q tile: 32 rows x 64B (waves 0,1 only — wave-uniform branch)
  if (wave < 2)
    gld16(q8g + ((size_t)bh*SEQ + i0)*HD + tid*16, q8s + tid*16);

  { // stage conv v window [d][i0-1 .. i0+32]
    int d = tid >> 2, part = tid & 3;
    const f16* vrow = vTg + ((size_t)(bh*HD) + d)*SEQ;
#pragma unroll
    for (int e = 0; e < 9; ++e) {
      int ss = part*9 + e;
      if (ss < 34) {
        int s = i0 - 1 + ss;
        vconv[d*34 + ss] = (s >= 0 && s < SEQ) ? vrow[s] : (f16)0.0f;
      }
    }
  }
  __syncthreads();

  // q rows {iL, iL+16} into regs (32 u32) — read from LDS once
  unsigned qr[2][16];
#pragma unroll
  for (int n = 0; n < 2; ++n)
#pragma unroll
    for (int c4 = 0; c4 < 4; ++c4) {
      uint4 t = *(const uint4*)&q8s[(iL + n*16)*64 + c4*16];
      qr[n][c4*4+0] = t.x; qr[n][c4*4+1] = t.y; qr[n][c4*4+2] = t.z; qr[n][c4*4+3] = t.w;
    }

  float rs[2] = {0.f, 0.f};
  floatx4 pacc[2] = {};

  for (int jb = 0; jb < 8; ++jb) {
    const int j0 = jb * 128;
    __syncthreads();                       // prev iter done with k8s/sfrag
#pragma unroll
    for (int r = 0; r < 2; ++r) {          // k tile: 128 rows x 64B
      int slot = r*256 + tid;
      gld16(k8g + ((size_t)bh*SEQ + j0)*HD + slot*16, k8s + slot*16);
    }
    __syncthreads();                       // staging complete

    // ---- phase 1: SAD distances, 2 i x 8 j per thread (k reads broadcast) ----
    unsigned sacc[2][8] = {};
#pragma unroll
    for (int c4 = 0; c4 < 4; ++c4) {
      uint4 kk[8];
#pragma unroll
      for (int jj = 0; jj < 8; ++jj)
        kk[jj] = *(const uint4*)&k8s[(jt*8 + jj)*64 + c4*16];   // 16-lane broadcast
#pragma unroll
      for (int n = 0; n < 2; ++n)
#pragma unroll
        for (int jj = 0; jj < 8; ++jj) {
          sacc[n][jj] = sadU8(qr[n][c4*4+0], kk[jj].x, sacc[n][jj]);
          sacc[n][jj] = sadU8(qr[n][c4*4+1], kk[jj].y, sacc[n][jj]);
          sacc[n][jj] = sadU8(qr[n][c4*4+2], kk[jj].z, sacc[n][jj]);
          sacc[n][jj] = sadU8(qr[n][c4*4+3], kk[jj].w, sacc[n][jj]);
        }
    }
    // kern = exp(-sad/256) -> exp2(-sad*log2e/256)
#pragma unroll
    for (int n = 0; n < 2; ++n) {
      half8 sv;
#pragma unroll
      for (int jj = 0; jj < 8; ++jj) {
        float sf = exp2f(-0.0056355275f * (float)sacc[n][jj]);
        rs[n] += sf;
        sv[jj] = (f16)sf;
      }
      // A-frag layout: slot = (m-tile*4 + ks)*64 + (qj*16 + iL), lane-contiguous
      *(half8*)&sfrag[((n*4 + ksj)*64 + qj*16 + iL)*8] = sv;
    }
    __syncthreads();                       // scores ready

    // ---- phase 2: PV via MFMA; B-frags direct from global (L2-hot) ----
#pragma unroll
    for (int ks = 0; ks < 4; ++ks) {
      half8 a = *(const half8*)&sfrag[((mtb*4 + ks)*64 + lane)*8];
#pragma unroll
      for (int nt = 0; nt < 2; ++nt) {
        int d = (ntb*2 + nt)*16 + li;
        half8 bfr = *(const half8*)(vTg + ((size_t)(bh*HD) + d)*SEQ + j0 + (ks*4 + lq)*8);
        pacc[nt] = __builtin_amdgcn_mfma_f32_16x16x32_f16(a, bfr, pacc[nt], 0, 0, 0);
      }
    }
  }

  // rowsum reduction across the 16 j-slices
#pragma unroll
  for (int n = 0; n < 2; ++n) rspart[(iL + n*16)*16 + jt] = rs[n];
  __syncthreads();
  if (tid < 32) {
    float s = 0.f;
#pragma unroll
    for (int t = 0; t < 16; ++t) s += rspart[tid*16 + t];
    rowsumS[tid] = s + 1e-6f;
  }
  __syncthreads();

  // epilogue: normalize + depthwise conv + store y16 [b,s,h*64+d]
  // wave owns i in [mtb*16,+16), d in [ntb*32,+32)
  const int b = bh >> 4, h = bh & 15;
#pragma unroll
  for (int nt = 0; nt < 2; ++nt) {
    int d = (ntb*2 + nt)*16 + li;
    int c = h*64 + d;
    float w0 = dwcw[c*3+0], w1 = dwcw[c*3+1], w2 = dwcw[c*3+2], cb = dwcb[c];
#pragma unroll
    for (int r = 0; r < 4; ++r) {
      int ii = mtb*16 + lq*4 + r;
      float val = pacc[nt][r] / rowsumS[ii];
      val += w0*(float)vconv[d*34 + ii] + w1*(float)vconv[d*34 + ii + 1]
           + w2*(float)vconv[d*34 + ii + 2] + cb;
      int s = i0 + ii;
      y16[((size_t)(b*SEQ + s))*DIMC + c] = (f16)val;
    }
  }
}

extern "C" void kernel_launch(void* const* d_in, const int* in_sizes, int n_in,
                              void* d_out, int out_size, void* d_ws, size_t ws_size,
                              hipStream_t stream) {
  const float* x      = (const float*)d_in[0];
  const float* qkv_w  = (const float*)d_in[1];
  const float* qkv_b  = (const float*)d_in[2];
  const float* proj_w = (const float*)d_in[3];
  const float* proj_b = (const float*)d_in[4];
  const float* dwc_w  = (const float*)d_in[5];
  const float* dwc_b  = (const float*)d_in[6];
  float* out = (float*)d_out;

  char* ws = (char*)d_ws;
  f16* x16  = (f16*)(ws);                         //  4 MB
  f16* wq16 = (f16*)(ws + (4ll<<20));             //  6 MB
  f16* wp16 = (f16*)(ws + (10ll<<20));            //  2 MB
  unsigned char* q8 = (unsigned char*)(ws + (12ll<<20));  // 2 MB
  unsigned char* k8 = (unsigned char*)(ws + (14ll<<20));  // 2 MB
  f16* vT   = (f16*)(ws + (16ll<<20));            //  4 MB
  f16* y16  = (f16*)(ws + (20ll<<20));            //  4 MB (total 24 MB)

  cvt_kernel<<<6144, 256, 0, stream>>>(x, qkv_w, proj_w, x16, wq16, wp16);
  gemm_kernel<64,128,0><<<dim3(24, 32), 256, 0, stream>>>(x16, wq16, qkv_b, q8, k8, vT, nullptr, DIMC);
  attn_kernel<<<dim3(32, 32), 256, 0, stream>>>(q8, k8, vT, dwc_w, dwc_b, y16);
  gemm_kernel<64,64,1><<<dim3(16, 32), 256, 0, stream>>>(y16, wp16, proj_b, nullptr, nullptr, nullptr, out, DIMC);
}